// Round 2
// baseline (138.495 us; speedup 1.0000x reference)
//
#include <hip/hip_runtime.h>

// ---------------------------------------------------------------------------
// Sparse3DNA: x->QKV proj (bf16 MFMA GEMM), 3x3x3 causal window attention
// (+BOS), output proj. Shapes: b=2, T=4096 (4x32x32), DIM=512, 8 heads x 64.
// R16: attn v8 — ONE wave per (b, token), all 8 heads. Phase 1 QK dot via
// mfma_f32_16x16x32_bf16: B-frag rows = 16 window slots (slot=lane&15,
// kchunk=quad*8 — same fragment layout as gemm_nt's bLds), A-frag lane-row-
// UNIFORM (all lanes load same Q head) so every C row = the score row and
// acc[0] is valid on all lanes. Softmax reduce = shfl_xor 1/2/4/8. Phase 2:
// one dwordx4/lane covers the full 1KB V row (15 loads/token vs 30),
// padded P-table (17-float rows, bank-conflict-free), packed-f32x2 fma.
// GEMMs/cast = R9/R13 + R15 XCD swizzle (confirmed −2.3us). F~75us fixed.
// ---------------------------------------------------------------------------

#define T_TOK   4096
#define DIM     512
#define NQKV    1536

typedef unsigned short u16;
typedef unsigned int   u32;
typedef unsigned long long u64;
typedef __attribute__((ext_vector_type(8))) short short8;   // 8 bf16 (4 VGPR)
typedef __attribute__((ext_vector_type(4))) float f32x4;
typedef __attribute__((ext_vector_type(2))) float f32x2;

__device__ __forceinline__ u16 f2bf(float f) {           // RNE float->bf16
    u32 u = __float_as_uint(f);
    return (u16)((u + 0x7fffu + ((u >> 16) & 1u)) >> 16);
}
__device__ __forceinline__ float b2f(u16 u) {
    return __uint_as_float(((u32)u) << 16);
}

__device__ __forceinline__ void gload_lds16(const void* g, void* l) {
    // async global->LDS, 16B/lane; LDS dest = wave-uniform base + lane*16
    __builtin_amdgcn_global_load_lds(
        (const __attribute__((address_space(1))) void*)g,
        (__attribute__((address_space(3))) void*)l, 16, 0, 0);
}

// ---------------------------------------------------------------------------
// merged cast kernel.
//  blocks [0,4096): x fp32 -> bf16 (vectorized)
//  blocks [4096,4288): Wt[n][k] = [Wq|Wk|Wv](k,n), LDS-tiled 64x64 transpose
//  blocks [4288,4352): Wot[n][k] = Wo[k][n], same
// ---------------------------------------------------------------------------
__global__ void cast_all_kernel(const float4* __restrict__ x,
                                const float* __restrict__ Wq, const float* __restrict__ Wkv,
                                const float* __restrict__ Wo,
                                u16* __restrict__ xb, u16* __restrict__ Wt,
                                u16* __restrict__ Wot) {
    __shared__ float S[64 * 65];
    int blk = blockIdx.x;
    int tid = threadIdx.x;
    if (blk < 4096) {
        int i = blk * 256 + tid;                  // 1,048,576 float4s
        float4 v = x[i];
        u64 pack = (u64)f2bf(v.x) | ((u64)f2bf(v.y) << 16) |
                   ((u64)f2bf(v.z) << 32) | ((u64)f2bf(v.w) << 48);
        ((u64*)xb)[i] = pack;
        return;
    }
    int isWo = blk >= 4288;
    int tIdx = isWo ? (blk - 4288) : (blk - 4096);
    int tn = tIdx >> 3, tk = tIdx & 7;            // n-tile, k-tile
    #pragma unroll
    for (int p = 0; p < 16; ++p) {                // stage, coalesced over n
        int kl = p * 4 + (tid >> 6), nl = tid & 63;
        int gk = tk * 64 + kl, gn = tn * 64 + nl;
        float v;
        if (isWo)            v = Wo[gk * 512 + gn];
        else if (gn < 512)   v = Wq[gk * 512 + gn];
        else                 v = Wkv[gk * 1024 + (gn - 512)];
        S[kl * 65 + nl] = v;
    }
    __syncthreads();
    u16* dst = isWo ? Wot : Wt;
    #pragma unroll
    for (int p = 0; p < 16; ++p) {                // write, coalesced over k
        int nl = p * 4 + (tid >> 6), kl = tid & 63;
        dst[(size_t)(tn * 64 + nl) * 512 + tk * 64 + kl] = f2bf(S[kl * 65 + nl]);
    }
}

// ---------------------------------------------------------------------------
// NT GEMM, double-buffered (best of 6 variants): C = A * B^T, K=512, bf16.
// BMxBN / block, 4 waves (2x2), mfma 16x16x32, BK=32, XOR-swizzled LDS.
// K-loop: stage(ks+1 -> buf^1); s_waitcnt vmcnt(NLD); s_barrier; frags+MFMA;
// lgkmcnt(0); s_barrier.  MODE 0: bf16 store. MODE 1: fp32 store + bias.
// R15: XCD-chunked block swizzle (bijective, nblk%8==0): each XCD owns a
// contiguous run of bm-panels -> A panel (1MB) + B panel L2-resident.
// ---------------------------------------------------------------------------
template <int BM, int BN, int MODE>
__global__ __launch_bounds__(256)
void gemm_nt(const u16* __restrict__ A, const u16* __restrict__ B,
             void* __restrict__ Cv, const float* __restrict__ bias,
             int lda, int ldb, int ldc) {
    constexpr int K = 512, BK = 32, KSTEPS = K / BK;
    constexpr int ACH = BM * 4;                  // A 16B-chunks per K-step
    constexpr int NCH = (BM + BN) * 4;
    constexpr int NLD = NCH / 256;               // chunks per thread per stage
    constexpr int ABYTES = BM * 64;
    constexpr int HALF = (BM + BN) * 64;         // one buffer
    constexpr int MI = BM / 32, NJ = BN / 32;
    __shared__ __align__(16) char lds[2 * HALF];
    const int tid  = threadIdx.x;
    const int lane = tid & 63, wave = tid >> 6;
    const int quad = lane >> 4, mrow = lane & 15;
    const int wm = wave >> 1, wn = wave & 1;

    // XCD-aware bijective swizzle: consecutive blocks round-robin XCDs, so
    // give XCD x the contiguous work chunk [x*nblk/8, (x+1)*nblk/8).
    const int nblk = gridDim.x * gridDim.y;
    int lid = blockIdx.y * gridDim.x + blockIdx.x;
    if (!(nblk & 7)) lid = (lid & 7) * (nblk >> 3) + (lid >> 3);
    const int bm = lid / (int)gridDim.x, bn = lid % (int)gridDim.x;

    const char* gptr[NLD];
    char*       lptr[NLD];
    #pragma unroll
    for (int it = 0; it < NLD; ++it) {
        int c   = it * 256 + tid;                // chunk id, lane-consecutive
        int inB = (c >= ACH);
        int a   = inB ? c - ACH : c;
        int r   = a >> 2;                        // tile row
        int kc  = ((a & 3) - (r >> 1)) & 3;      // inverse swizzle
        int row = (inB ? bn * BN : bm * BM) + r;
        const u16* base = inB ? B : A;
        int ld = inB ? ldb : lda;
        gptr[it] = (const char*)(base + (size_t)row * ld + kc * 8);
        lptr[it] = (char*)lds + (it * 256 + wave * 64) * 16;   // wave-uniform
    }
    const char* aLds[MI];
    const char* bLds[NJ];
    #pragma unroll
    for (int i = 0; i < MI; ++i) {
        int ra = wm * (BM / 2) + i * 16 + mrow;
        aLds[i] = lds + (ra * 4 + ((quad + (ra >> 1)) & 3)) * 16;
    }
    #pragma unroll
    for (int j = 0; j < NJ; ++j) {
        int rb = wn * (BN / 2) + j * 16 + mrow;
        bLds[j] = lds + ABYTES + (rb * 4 + ((quad + (rb >> 1)) & 3)) * 16;
    }

    f32x4 acc[MI][NJ] = {};
    #pragma unroll
    for (int it = 0; it < NLD; ++it)             // prologue: stage 0 -> buf 0
        gload_lds16(gptr[it], lptr[it]);

    #pragma unroll
    for (int ks = 0; ks < KSTEPS; ++ks) {
        const int cur = ks & 1;
        if (ks + 1 < KSTEPS) {                   // prefetch next stage
            #pragma unroll
            for (int it = 0; it < NLD; ++it)
                gload_lds16(gptr[it] + 2 * (ks + 1) * BK, lptr[it] + (cur ^ 1) * HALF);
            asm volatile("s_waitcnt vmcnt(%0)" :: "i"(NLD) : "memory");
        } else {
            asm volatile("s_waitcnt vmcnt(0)" ::: "memory");
        }
        asm volatile("s_barrier" ::: "memory");  // stage ks visible to all

        short8 af[MI], bf[NJ];
        #pragma unroll
        for (int i = 0; i < MI; ++i) af[i] = *(const short8*)(aLds[i] + cur * HALF);
        #pragma unroll
        for (int j = 0; j < NJ; ++j) bf[j] = *(const short8*)(bLds[j] + cur * HALF);
        #pragma unroll
        for (int i = 0; i < MI; ++i)
            #pragma unroll
            for (int j = 0; j < NJ; ++j)
                acc[i][j] = __builtin_amdgcn_mfma_f32_16x16x32_bf16(af[i], bf[j], acc[i][j], 0, 0, 0);
        asm volatile("s_waitcnt lgkmcnt(0)" ::: "memory");
        asm volatile("s_barrier" ::: "memory");  // all waves done reading buf
    }

    // epilogue: D row = quad*4 + reg, col = lane&15 (m89-verified layout)
    #pragma unroll
    for (int i = 0; i < MI; ++i) {
        #pragma unroll
        for (int j = 0; j < NJ; ++j) {
            int colg = bn * BN + wn * (BN / 2) + j * 16 + mrow;
            #pragma unroll
            for (int r = 0; r < 4; ++r) {
                int rowg = bm * BM + wm * (BM / 2) + i * 16 + quad * 4 + r;
                if (MODE == 0) {
                    ((u16*)Cv)[(size_t)rowg * ldc + colg] = f2bf(acc[i][j][r]);
                } else {
                    ((float*)Cv)[(size_t)rowg * ldc + colg] = acc[i][j][r] + bias[colg];
                }
            }
        }
    }
}

// ---------------------------------------------------------------------------
// Attention v8: ONE wave per (b, ti) — 8192 waves, 2048 blocks (XCD swizzle).
// slot = lane&15, kchunk quad = lane>>4 (matches gemm bLds B-frag layout).
// Phase 1: per head h: A-frag = Q[t+1][h*64 + quad*8 ..] (lane-row-uniform ->
//   all 16 C rows identical), B-frag = K[p_slot][h*64 + quad*8 ..];
//   2 chained mfma (K=64) -> acc[0] = S[h][slot] on every lane. 16 mfma
//   replace ~384 VALU dot insts. Softmax: shfl_xor 1/2/4/8 over 16 slots
//   (replicated per quad). P-table Pns[wave][h*17+slot] (pad 17: banks
//   h*17%32 all distinct -> conflict-free broadcast reads).
// Phase 2: lane = (head = lane>>3, dims (lane&7)*8..+7). Per slot:
//   readlane(voff, slot) + ds_read_b32(pj) + ONE dwordx4 (1KB V row / wave)
//   + 8 unpack + 4 packed-f32x2 fma. Store: one dwordx4 per lane.
// ---------------------------------------------------------------------------
__global__ __launch_bounds__(256)
void attn_kernel(const u16* __restrict__ QKV, u16* __restrict__ O) {
    __shared__ float Pns[4][8 * 17];
    const int wave = threadIdx.x >> 6;
    // bijective XCD swizzle: 2048 blocks, XCD x owns contiguous 256-block run
    const int bsw = ((blockIdx.x & 7) << 8) | (blockIdx.x >> 3);
    const int wid  = bsw * 4 + wave;             // 0..8191
    const int lane = threadIdx.x & 63;
    const int b  = wid >> 12;             // 2
    const int ti = wid & 4095;            // 4096
    const size_t baseQ = (size_t)b * T_TOK * NQKV;
    const size_t baseO = (size_t)b * T_TOK * DIM;

    if (ti == 0) {                        // output row 0 = bos_v (1KB copy)
        const uint4* src = (const uint4*)(QKV + baseQ + 1024);
        uint4* dst = (uint4*)(O + baseO);
        dst[lane] = src[lane];
        return;
    }
    const int t = ti - 1;                 // grid position, 0..4094
    const int f = t >> 10, hh = (t >> 5) & 31, ww = t & 31;

    // ---- per-lane slot decode: slot j = lane&15 (j==0 BOS, j==15 dead)
    const int j = lane & 15, quad = lane >> 4;
    int jm1 = j - 1;
    int dh9 = ((jm1 * 11) >> 5) - 1;      // j in 1..9: (j-1)/3 - 1
    int dw9 = jm1 - (dh9 + 1) * 3 - 1;    // j in 1..9: (j-1)%3 - 1
    int df = (j >= 1 && j <= 9) ? -1 : 0;
    int dh = (j >= 1 && j <= 9) ? dh9 : ((j >= 10 && j <= 12) ? -1 : 0);
    int dw = (j >= 1 && j <= 9) ? dw9 :
             ((j >= 10 && j <= 12) ? (j - 11) : ((j == 13) ? -1 : 0));
    int nf = f + df, nh = hh + dh, nw = ww + dw;
    int valid = (nf >= 0) && ((unsigned)nh < 32u) && ((unsigned)nw < 32u)
                && (j >= 1) && (j <= 14);
    int p = valid ? (t + 1 + df * 1024 + dh * 32 + dw) : 0;   // j==0 -> BOS
    int score_on = valid || (j == 0);

    // ---- phase 1: S[h][slot] via mfma, 8 heads x 2 (K=64)
    const u16* qrow = QKV + baseQ + (size_t)(t + 1) * NQKV;       // Q row t+1
    const u16* krow = QKV + baseQ + (size_t)p * NQKV + 512;       // K row p
    const f32x4 zero = {0.f, 0.f, 0.f, 0.f};
    float s[8];
    #pragma unroll
    for (int h = 0; h < 8; ++h) {
        short8 qa = *(const short8*)(qrow + h * 64 + quad * 8);        // dims 0-31
        short8 ka = *(const short8*)(krow + h * 64 + quad * 8);
        short8 qb = *(const short8*)(qrow + h * 64 + 32 + quad * 8);   // dims 32-63
        short8 kb = *(const short8*)(krow + h * 64 + 32 + quad * 8);
        f32x4 acc = __builtin_amdgcn_mfma_f32_16x16x32_bf16(qa, ka, zero, 0, 0, 0);
        acc = __builtin_amdgcn_mfma_f32_16x16x32_bf16(qb, kb, acc, 0, 0, 0);
        s[h] = acc[0] * 0.125f;           // SCALE; valid on all lanes
    }
    #pragma unroll
    for (int h = 0; h < 8; ++h) s[h] = score_on ? s[h] : -3.0e38f;

    float m[8], pe[8], l[8];
    #pragma unroll
    for (int h = 0; h < 8; ++h) m[h] = s[h];
    #pragma unroll
    for (int off = 1; off <= 8; off <<= 1)
        #pragma unroll
        for (int h = 0; h < 8; ++h) m[h] = fmaxf(m[h], __shfl_xor(m[h], off));
    #pragma unroll
    for (int h = 0; h < 8; ++h) { pe[h] = __expf(s[h] - m[h]); l[h] = pe[h]; }
    #pragma unroll
    for (int off = 1; off <= 8; off <<= 1)
        #pragma unroll
        for (int h = 0; h < 8; ++h) l[h] += __shfl_xor(l[h], off);

    u32 voff = (u32)p * 3072u;            // byte offset of V row p (slot=lane)

    if (lane < 16) {                      // quad 0 writes the P table
        #pragma unroll
        for (int h = 0; h < 8; ++h)
            Pns[wave][h * 17 + lane] = pe[h] * __frcp_rn(l[h]);
    }
    asm volatile("s_waitcnt lgkmcnt(0)" ::: "memory");

    // ---- phase 2: PV; lane = (head = lane>>3, dims (lane&7)*8 .. +7)
    const float* ptab = &Pns[wave][(lane >> 3) * 17];
    const char* vbase = (const char*)(QKV + baseQ + 1024) + lane * 16;
    f32x2 a01 = {0.f, 0.f}, a23 = {0.f, 0.f}, a45 = {0.f, 0.f}, a67 = {0.f, 0.f};
    #pragma unroll
    for (int jj = 0; jj < 15; ++jj) {
        u32 o = (u32)__builtin_amdgcn_readlane((int)voff, jj);
        float pj = ptab[jj];
        uint4 v = *(const uint4*)(vbase + o);     // 8 dims of lane's head
        f32x2 p2 = {pj, pj};
        f32x2 v0 = {__uint_as_float(v.x << 16), __uint_as_float(v.x & 0xffff0000u)};
        f32x2 v1 = {__uint_as_float(v.y << 16), __uint_as_float(v.y & 0xffff0000u)};
        f32x2 v2 = {__uint_as_float(v.z << 16), __uint_as_float(v.z & 0xffff0000u)};
        f32x2 v3 = {__uint_as_float(v.w << 16), __uint_as_float(v.w & 0xffff0000u)};
        a01 = __builtin_elementwise_fma(p2, v0, a01);
        a23 = __builtin_elementwise_fma(p2, v1, a23);
        a45 = __builtin_elementwise_fma(p2, v2, a45);
        a67 = __builtin_elementwise_fma(p2, v3, a67);
    }
    u32 r0 = (u32)f2bf(a01.x) | ((u32)f2bf(a01.y) << 16);
    u32 r1 = (u32)f2bf(a23.x) | ((u32)f2bf(a23.y) << 16);
    u32 r2 = (u32)f2bf(a45.x) | ((u32)f2bf(a45.y) << 16);
    u32 r3 = (u32)f2bf(a67.x) | ((u32)f2bf(a67.y) << 16);
    uint4 pack = {r0, r1, r2, r3};
    *(uint4*)((char*)(O + baseO) + (size_t)ti * (DIM * 2) + lane * 16) = pack;
}

// ---------------------------------------------------------------------------
// launch: cast -> gemm1 (QKV) -> attn -> gemm2 (out proj + bias)
// ws layout (bytes): xb 8M @0 | Wt 1.5M @8388608 | Wot 0.5M @9961472 |
//                    QKV 24M @10485760 | O aliases xb @0   (total ~34MB)
// ---------------------------------------------------------------------------
extern "C" void kernel_launch(void* const* d_in, const int* in_sizes, int n_in,
                              void* d_out, int out_size, void* d_ws, size_t ws_size,
                              hipStream_t stream) {
    const float* x   = (const float*)d_in[0];
    const float* Wq  = (const float*)d_in[1];
    const float* Wkv = (const float*)d_in[2];
    const float* Wo  = (const float*)d_in[3];
    const float* bo  = (const float*)d_in[4];
    float* out = (float*)d_out;
    char* ws = (char*)d_ws;

    u16* xb  = (u16*)(ws + 0);
    u16* Wt  = (u16*)(ws + 8388608);
    u16* Wot = (u16*)(ws + 9961472);
    u16* QKV = (u16*)(ws + 10485760);
    u16* O   = (u16*)(ws + 0);          // aliases xb (dead after gemm1)

    cast_all_kernel<<<dim3(4352), dim3(256), 0, stream>>>(
        (const float4*)x, Wq, Wkv, Wo, xb, Wt, Wot);
    gemm_nt<128, 128, 0><<<dim3(12, 64), dim3(256), 0, stream>>>(
        xb, Wt, (void*)QKV, nullptr, 512, 512, 1536);
    attn_kernel<<<dim3(2048), dim3(256), 0, stream>>>(QKV, O);
    gemm_nt<128, 64, 1><<<dim3(8, 64), dim3(256), 0, stream>>>(
        O, Wot, (void*)out, bo, 512, 512, 512);
}

// Round 3
// 129.150 us; speedup vs baseline: 1.0724x; 1.0724x over previous
//
#include <hip/hip_runtime.h>

// ---------------------------------------------------------------------------
// Sparse3DNA: x->QKV proj (bf16 MFMA GEMM), 3x3x3 causal window attention
// (+BOS), output proj. Shapes: b=2, T=4096 (4x32x32), DIM=512, 8 heads x 64.
// R17: attn = R15's v7 structure (proven 132.2us; R16's MFMA rewrite regressed
// +6.3us — VGPR/occupancy collapse) with the scalar unpack+fma QK dot replaced
// by v_dot2_f32_bf16 (1 inst / 2 dims vs 6) and phase-2 PV using packed
// v_pk_fma_f32 (f32x2). GEMMs/cast = R9/R13 + R15 XCD swizzle. F~75us fixed.
// ---------------------------------------------------------------------------

#define T_TOK   4096
#define DIM     512
#define NQKV    1536

typedef unsigned short u16;
typedef unsigned int   u32;
typedef unsigned long long u64;
typedef __attribute__((ext_vector_type(8))) short short8;   // 8 bf16 (4 VGPR)
typedef __attribute__((ext_vector_type(4))) float f32x4;
typedef __attribute__((ext_vector_type(2))) float f32x2;
typedef __attribute__((ext_vector_type(4))) u32 u32x4;

__device__ __forceinline__ u16 f2bf(float f) {           // RNE float->bf16
    u32 u = __float_as_uint(f);
    return (u16)((u + 0x7fffu + ((u >> 16) & 1u)) >> 16);
}
__device__ __forceinline__ float b2f(u16 u) {
    return __uint_as_float(((u32)u) << 16);
}
__device__ __forceinline__ float dot2bf(u32 q, u32 k, float c) {
    // c += q.lo*k.lo + q.hi*k.hi  (packed bf16 pair dot, VOP3P)
    float r = c;
    asm("v_dot2_f32_bf16 %0, %1, %2, %0" : "+v"(r) : "v"(q), "v"(k));
    return r;
}

__device__ __forceinline__ void gload_lds16(const void* g, void* l) {
    // async global->LDS, 16B/lane; LDS dest = wave-uniform base + lane*16
    __builtin_amdgcn_global_load_lds(
        (const __attribute__((address_space(1))) void*)g,
        (__attribute__((address_space(3))) void*)l, 16, 0, 0);
}

// ---------------------------------------------------------------------------
// merged cast kernel.
//  blocks [0,4096): x fp32 -> bf16 (vectorized)
//  blocks [4096,4288): Wt[n][k] = [Wq|Wk|Wv](k,n), LDS-tiled 64x64 transpose
//  blocks [4288,4352): Wot[n][k] = Wo[k][n], same
// ---------------------------------------------------------------------------
__global__ void cast_all_kernel(const float4* __restrict__ x,
                                const float* __restrict__ Wq, const float* __restrict__ Wkv,
                                const float* __restrict__ Wo,
                                u16* __restrict__ xb, u16* __restrict__ Wt,
                                u16* __restrict__ Wot) {
    __shared__ float S[64 * 65];
    int blk = blockIdx.x;
    int tid = threadIdx.x;
    if (blk < 4096) {
        int i = blk * 256 + tid;                  // 1,048,576 float4s
        float4 v = x[i];
        u64 pack = (u64)f2bf(v.x) | ((u64)f2bf(v.y) << 16) |
                   ((u64)f2bf(v.z) << 32) | ((u64)f2bf(v.w) << 48);
        ((u64*)xb)[i] = pack;
        return;
    }
    int isWo = blk >= 4288;
    int tIdx = isWo ? (blk - 4288) : (blk - 4096);
    int tn = tIdx >> 3, tk = tIdx & 7;            // n-tile, k-tile
    #pragma unroll
    for (int p = 0; p < 16; ++p) {                // stage, coalesced over n
        int kl = p * 4 + (tid >> 6), nl = tid & 63;
        int gk = tk * 64 + kl, gn = tn * 64 + nl;
        float v;
        if (isWo)            v = Wo[gk * 512 + gn];
        else if (gn < 512)   v = Wq[gk * 512 + gn];
        else                 v = Wkv[gk * 1024 + (gn - 512)];
        S[kl * 65 + nl] = v;
    }
    __syncthreads();
    u16* dst = isWo ? Wot : Wt;
    #pragma unroll
    for (int p = 0; p < 16; ++p) {                // write, coalesced over k
        int nl = p * 4 + (tid >> 6), kl = tid & 63;
        dst[(size_t)(tn * 64 + nl) * 512 + tk * 64 + kl] = f2bf(S[kl * 65 + nl]);
    }
}

// ---------------------------------------------------------------------------
// NT GEMM, double-buffered (best of 6 variants): C = A * B^T, K=512, bf16.
// BMxBN / block, 4 waves (2x2), mfma 16x16x32, BK=32, XOR-swizzled LDS.
// K-loop: stage(ks+1 -> buf^1); s_waitcnt vmcnt(NLD); s_barrier; frags+MFMA;
// lgkmcnt(0); s_barrier.  MODE 0: bf16 store. MODE 1: fp32 store + bias.
// R15: XCD-chunked block swizzle (bijective, nblk%8==0): each XCD owns a
// contiguous run of bm-panels -> A panel (1MB) + B panel L2-resident.
// ---------------------------------------------------------------------------
template <int BM, int BN, int MODE>
__global__ __launch_bounds__(256)
void gemm_nt(const u16* __restrict__ A, const u16* __restrict__ B,
             void* __restrict__ Cv, const float* __restrict__ bias,
             int lda, int ldb, int ldc) {
    constexpr int K = 512, BK = 32, KSTEPS = K / BK;
    constexpr int ACH = BM * 4;                  // A 16B-chunks per K-step
    constexpr int NCH = (BM + BN) * 4;
    constexpr int NLD = NCH / 256;               // chunks per thread per stage
    constexpr int ABYTES = BM * 64;
    constexpr int HALF = (BM + BN) * 64;         // one buffer
    constexpr int MI = BM / 32, NJ = BN / 32;
    __shared__ __align__(16) char lds[2 * HALF];
    const int tid  = threadIdx.x;
    const int lane = tid & 63, wave = tid >> 6;
    const int quad = lane >> 4, mrow = lane & 15;
    const int wm = wave >> 1, wn = wave & 1;

    // XCD-aware bijective swizzle: consecutive blocks round-robin XCDs, so
    // give XCD x the contiguous work chunk [x*nblk/8, (x+1)*nblk/8).
    const int nblk = gridDim.x * gridDim.y;
    int lid = blockIdx.y * gridDim.x + blockIdx.x;
    if (!(nblk & 7)) lid = (lid & 7) * (nblk >> 3) + (lid >> 3);
    const int bm = lid / (int)gridDim.x, bn = lid % (int)gridDim.x;

    const char* gptr[NLD];
    char*       lptr[NLD];
    #pragma unroll
    for (int it = 0; it < NLD; ++it) {
        int c   = it * 256 + tid;                // chunk id, lane-consecutive
        int inB = (c >= ACH);
        int a   = inB ? c - ACH : c;
        int r   = a >> 2;                        // tile row
        int kc  = ((a & 3) - (r >> 1)) & 3;      // inverse swizzle
        int row = (inB ? bn * BN : bm * BM) + r;
        const u16* base = inB ? B : A;
        int ld = inB ? ldb : lda;
        gptr[it] = (const char*)(base + (size_t)row * ld + kc * 8);
        lptr[it] = (char*)lds + (it * 256 + wave * 64) * 16;   // wave-uniform
    }
    const char* aLds[MI];
    const char* bLds[NJ];
    #pragma unroll
    for (int i = 0; i < MI; ++i) {
        int ra = wm * (BM / 2) + i * 16 + mrow;
        aLds[i] = lds + (ra * 4 + ((quad + (ra >> 1)) & 3)) * 16;
    }
    #pragma unroll
    for (int j = 0; j < NJ; ++j) {
        int rb = wn * (BN / 2) + j * 16 + mrow;
        bLds[j] = lds + ABYTES + (rb * 4 + ((quad + (rb >> 1)) & 3)) * 16;
    }

    f32x4 acc[MI][NJ] = {};
    #pragma unroll
    for (int it = 0; it < NLD; ++it)             // prologue: stage 0 -> buf 0
        gload_lds16(gptr[it], lptr[it]);

    #pragma unroll
    for (int ks = 0; ks < KSTEPS; ++ks) {
        const int cur = ks & 1;
        if (ks + 1 < KSTEPS) {                   // prefetch next stage
            #pragma unroll
            for (int it = 0; it < NLD; ++it)
                gload_lds16(gptr[it] + 2 * (ks + 1) * BK, lptr[it] + (cur ^ 1) * HALF);
            asm volatile("s_waitcnt vmcnt(%0)" :: "i"(NLD) : "memory");
        } else {
            asm volatile("s_waitcnt vmcnt(0)" ::: "memory");
        }
        asm volatile("s_barrier" ::: "memory");  // stage ks visible to all

        short8 af[MI], bf[NJ];
        #pragma unroll
        for (int i = 0; i < MI; ++i) af[i] = *(const short8*)(aLds[i] + cur * HALF);
        #pragma unroll
        for (int j = 0; j < NJ; ++j) bf[j] = *(const short8*)(bLds[j] + cur * HALF);
        #pragma unroll
        for (int i = 0; i < MI; ++i)
            #pragma unroll
            for (int j = 0; j < NJ; ++j)
                acc[i][j] = __builtin_amdgcn_mfma_f32_16x16x32_bf16(af[i], bf[j], acc[i][j], 0, 0, 0);
        asm volatile("s_waitcnt lgkmcnt(0)" ::: "memory");
        asm volatile("s_barrier" ::: "memory");  // all waves done reading buf
    }

    // epilogue: D row = quad*4 + reg, col = lane&15 (m89-verified layout)
    #pragma unroll
    for (int i = 0; i < MI; ++i) {
        #pragma unroll
        for (int j = 0; j < NJ; ++j) {
            int colg = bn * BN + wn * (BN / 2) + j * 16 + mrow;
            #pragma unroll
            for (int r = 0; r < 4; ++r) {
                int rowg = bm * BM + wm * (BM / 2) + i * 16 + quad * 4 + r;
                if (MODE == 0) {
                    ((u16*)Cv)[(size_t)rowg * ldc + colg] = f2bf(acc[i][j][r]);
                } else {
                    ((float*)Cv)[(size_t)rowg * ldc + colg] = acc[i][j][r] + bias[colg];
                }
            }
        }
    }
}

// ---------------------------------------------------------------------------
// Attention v7+dot2 (R17): one wave per (b, head-QUAD, ti) — 16384 waves.
// R15 XCD swizzle: each XCD owns 512 contiguous blocks -> window K/V reuse
// hits per-XCD L2 (confirmed −2.3us). Phase 1: slot decode shared; 4 heads'
// QK dot via v_dot2_f32_bf16 (8 insts/head vs 48 scalar); batched softmax
// shfl chains. Phase 2: lane = (head = lane>>4, dimgroup = lane&15); pj via
// per-wave LDS table; ONE dwordx2 load/slot covers all 4 heads; packed
// v_pk_fma_f32 accumulate; coalesced 8B store.
// ---------------------------------------------------------------------------
__global__ __launch_bounds__(256)
void attn_kernel(const u16* __restrict__ QKV, u16* __restrict__ O) {
    __shared__ float Pns[4][64];
    const int wave = threadIdx.x >> 6;
    // bijective XCD swizzle: 4096 blocks, XCD x owns contiguous 512-block run
    const int bsw = ((blockIdx.x & 7) << 9) | (blockIdx.x >> 3);
    const int wid  = bsw * 4 + wave;             // 0..16383
    const int lane = threadIdx.x & 63;
    const int b  = wid >> 13;             // 2
    const int hp = (wid >> 12) & 1;       // head quad (0..1)
    const int ti = wid & 4095;            // 4096
    const size_t baseQ = (size_t)b * T_TOK * NQKV;
    const size_t baseO = (size_t)b * T_TOK * DIM;
    const int hbase = hp * 256;           // u16-col of head quad start

    if (ti == 0) {                        // output row 0 = bos_v (4 heads)
        #pragma unroll
        for (int hd = 0; hd < 4; ++hd)
            O[baseO + hbase + hd * 64 + lane] =
                QKV[baseQ + 1024 + hbase + hd * 64 + lane];
        return;
    }
    const int t = ti - 1;                 // grid position, 0..4094
    const int f = t >> 10, hh = (t >> 5) & 31, ww = t & 31;

    // ---- per-lane slot decode (wave-uniform t; j varies per lane) — shared
    const int j = lane >> 2, g = lane & 3;
    int jm1 = j - 1;
    int dh9 = ((jm1 * 11) >> 5) - 1;      // j in 1..9: (j-1)/3 - 1
    int dw9 = jm1 - (dh9 + 1) * 3 - 1;    // j in 1..9: (j-1)%3 - 1
    int df = (j >= 1 && j <= 9) ? -1 : 0;
    int dh = (j >= 1 && j <= 9) ? dh9 : ((j >= 10 && j <= 12) ? -1 : 0);
    int dw = (j >= 1 && j <= 9) ? dw9 :
             ((j >= 10 && j <= 12) ? (j - 11) : ((j == 13) ? -1 : 0));
    int nf = f + df, nh = hh + dh, nw = ww + dw;
    int valid = (nf >= 0) && ((unsigned)nh < 32u) && ((unsigned)nw < 32u)
                && (j >= 1) && (j <= 14);
    int p = valid ? (t + 1 + df * 1024 + dh * 32 + dw) : 0;   // j==0 -> BOS
    int score_on = valid || (j == 0);

    // ---- phase 1: scores, four heads interleaved, packed bf16 dot2
    const u16* qbase = QKV + baseQ + (size_t)(t + 1) * NQKV + hbase + g * 16;
    const u16* kbase = QKV + baseQ + (size_t)p * NQKV + 512 + hbase + g * 16;
    u32x4 qa[4], qb[4], ka[4], kb[4];
    #pragma unroll
    for (int hd = 0; hd < 4; ++hd) {
        qa[hd] = *(const u32x4*)(qbase + hd * 64);
        qb[hd] = *(const u32x4*)(qbase + hd * 64 + 8);
        ka[hd] = *(const u32x4*)(kbase + hd * 64);
        kb[hd] = *(const u32x4*)(kbase + hd * 64 + 8);
    }
    float s[4] = {};
    #pragma unroll
    for (int i = 0; i < 4; ++i)
        #pragma unroll
        for (int hd = 0; hd < 4; ++hd) {
            s[hd] = dot2bf(qa[hd][i], ka[hd][i], s[hd]);
            s[hd] = dot2bf(qb[hd][i], kb[hd][i], s[hd]);
        }
    #pragma unroll
    for (int hd = 0; hd < 4; ++hd) {
        s[hd] += __shfl_xor(s[hd], 1);
        s[hd] += __shfl_xor(s[hd], 2);    // 4 g-lanes of slot j hold dot_j
        s[hd] *= 0.125f;                  // SCALE
        s[hd] = score_on ? s[hd] : -3.0e38f;
    }
    float m[4] = {s[0], s[1], s[2], s[3]};
    #pragma unroll
    for (int off = 4; off <= 32; off <<= 1)
        #pragma unroll
        for (int hd = 0; hd < 4; ++hd)
            m[hd] = fmaxf(m[hd], __shfl_xor(m[hd], off));
    float pe[4], l[4];
    #pragma unroll
    for (int hd = 0; hd < 4; ++hd) {
        pe[hd] = __expf(s[hd] - m[hd]);   // masked lanes -> 0
        l[hd] = pe[hd];
    }
    #pragma unroll
    for (int off = 4; off <= 32; off <<= 1)
        #pragma unroll
        for (int hd = 0; hd < 4; ++hd)
            l[hd] += __shfl_xor(l[hd], off);
    u32 voff = (u32)p * 3072u;            // byte offset of V row p (shared)

    // ---- pj table: Pns[wave][hd*16 + slot], written by g==0 lanes
    if ((lane & 3) == 0) {
        int slot = lane >> 2;
        #pragma unroll
        for (int hd = 0; hd < 4; ++hd)
            Pns[wave][hd * 16 + slot] = pe[hd] * __frcp_rn(l[hd]);
    }
    asm volatile("s_waitcnt lgkmcnt(0)" ::: "memory");

    // ---- phase 2: PV; lane = (head = lane>>4, dims (lane&15)*4 .. +3)
    const float* ptab = &Pns[wave][(lane >> 4) * 16];
    const char* vrow = (const char*)(QKV + baseQ + 1024 + hbase) + lane * 8;
    f32x2 a01 = {0.f, 0.f}, a23 = {0.f, 0.f};
    #pragma unroll
    for (int jj = 0; jj < 15; ++jj) {
        u32 o = (u32)__builtin_amdgcn_readlane((int)voff, jj * 4);
        float pj = ptab[jj];
        u64 v = *(const u64*)(vrow + o);          // 4 dims of lane's head
        u32 lo = (u32)v, hi = (u32)(v >> 32);
        f32x2 p2 = {pj, pj};
        f32x2 v0 = {__uint_as_float(lo << 16), __uint_as_float(lo & 0xffff0000u)};
        f32x2 v1 = {__uint_as_float(hi << 16), __uint_as_float(hi & 0xffff0000u)};
        a01 = __builtin_elementwise_fma(p2, v0, a01);
        a23 = __builtin_elementwise_fma(p2, v1, a23);
    }
    u64 pack = (u64)f2bf(a01.x) | ((u64)f2bf(a01.y) << 16) |
               ((u64)f2bf(a23.x) << 32) | ((u64)f2bf(a23.y) << 48);
    *(u64*)((char*)(O + baseO + (size_t)ti * DIM + hbase) + lane * 8) = pack;
}

// ---------------------------------------------------------------------------
// launch: cast -> gemm1 (QKV) -> attn -> gemm2 (out proj + bias)
// ws layout (bytes): xb 8M @0 | Wt 1.5M @8388608 | Wot 0.5M @9961472 |
//                    QKV 24M @10485760 | O aliases xb @0   (total ~34MB)
// ---------------------------------------------------------------------------
extern "C" void kernel_launch(void* const* d_in, const int* in_sizes, int n_in,
                              void* d_out, int out_size, void* d_ws, size_t ws_size,
                              hipStream_t stream) {
    const float* x   = (const float*)d_in[0];
    const float* Wq  = (const float*)d_in[1];
    const float* Wkv = (const float*)d_in[2];
    const float* Wo  = (const float*)d_in[3];
    const float* bo  = (const float*)d_in[4];
    float* out = (float*)d_out;
    char* ws = (char*)d_ws;

    u16* xb  = (u16*)(ws + 0);
    u16* Wt  = (u16*)(ws + 8388608);
    u16* Wot = (u16*)(ws + 9961472);
    u16* QKV = (u16*)(ws + 10485760);
    u16* O   = (u16*)(ws + 0);          // aliases xb (dead after gemm1)

    cast_all_kernel<<<dim3(4352), dim3(256), 0, stream>>>(
        (const float4*)x, Wq, Wkv, Wo, xb, Wt, Wot);
    gemm_nt<128, 128, 0><<<dim3(12, 64), dim3(256), 0, stream>>>(
        xb, Wt, (void*)QKV, nullptr, 512, 512, 1536);
    attn_kernel<<<dim3(4096), dim3(256), 0, stream>>>(QKV, O);
    gemm_nt<128, 64, 1><<<dim3(8, 64), dim3(256), 0, stream>>>(
        O, Wot, (void*)out, bo, 512, 512, 512);
}

// Round 4
// 127.719 us; speedup vs baseline: 1.0844x; 1.0112x over previous
//
#include <hip/hip_runtime.h>

// ---------------------------------------------------------------------------
// Sparse3DNA: x->QKV proj (bf16 MFMA GEMM), 3x3x3 causal window attention
// (+BOS), output proj. Shapes: b=2, T=4096 (4x32x32), DIM=512, 8 heads x 64.
// R18: fuse x fp32->bf16 cast INTO gemm1. gemm1's A operand is reg-staged
// from fp32 x (4x dwordx4/thread, pipelined 2 stages ahead), converted with
// v_cvt_pk_bf16_f32 (RNE, identical to f2bf), ds_write_b128 into the SAME
// swizzled LDS layout (frag reads / MFMA / barriers / epilogue untouched).
// B keeps global_load_lds. vmcnt: 6 newest ops = {B(ks+1)x2, A(ks+2)x4} ->
// vmcnt(6) steady / 2 / 0 tail. Cast kernel shrinks 4352->256 blocks.
// attn = R17 (v7+dot2, proven 129.1us). R15 XCD swizzles kept. F~90us fixed.
// ---------------------------------------------------------------------------

#define T_TOK   4096
#define DIM     512
#define NQKV    1536

typedef unsigned short u16;
typedef unsigned int   u32;
typedef unsigned long long u64;
typedef __attribute__((ext_vector_type(8))) short short8;   // 8 bf16 (4 VGPR)
typedef __attribute__((ext_vector_type(4))) float f32x4;
typedef __attribute__((ext_vector_type(2))) float f32x2;
typedef __attribute__((ext_vector_type(4))) u32 u32x4;

__device__ __forceinline__ u16 f2bf(float f) {           // RNE float->bf16
    u32 u = __float_as_uint(f);
    return (u16)((u + 0x7fffu + ((u >> 16) & 1u)) >> 16);
}
__device__ __forceinline__ u32 cvtpk(float lo, float hi) {  // 2x f32 -> packed bf16 (RNE)
    u32 r;
    asm("v_cvt_pk_bf16_f32 %0, %1, %2" : "=v"(r) : "v"(lo), "v"(hi));
    return r;
}
__device__ __forceinline__ float dot2bf(u32 q, u32 k, float c) {
    // c += q.lo*k.lo + q.hi*k.hi  (packed bf16 pair dot, VOP3P)
    float r = c;
    asm("v_dot2_f32_bf16 %0, %1, %2, %0" : "+v"(r) : "v"(q), "v"(k));
    return r;
}

__device__ __forceinline__ void gload_lds16(const void* g, void* l) {
    // async global->LDS, 16B/lane; LDS dest = wave-uniform base + lane*16
    __builtin_amdgcn_global_load_lds(
        (const __attribute__((address_space(1))) void*)g,
        (__attribute__((address_space(3))) void*)l, 16, 0, 0);
}

// ---------------------------------------------------------------------------
// weight cast kernel (x-cast now fused into gemm1).
//  blocks [0,192): Wt[n][k] = [Wq|Wk|Wv](k,n), LDS-tiled 64x64 transpose
//  blocks [192,256): Wot[n][k] = Wo[k][n], same
// ---------------------------------------------------------------------------
__global__ void cast_all_kernel(const float* __restrict__ Wq, const float* __restrict__ Wkv,
                                const float* __restrict__ Wo,
                                u16* __restrict__ Wt, u16* __restrict__ Wot) {
    __shared__ float S[64 * 65];
    int blk = blockIdx.x;
    int tid = threadIdx.x;
    int isWo = blk >= 192;
    int tIdx = isWo ? (blk - 192) : blk;
    int tn = tIdx >> 3, tk = tIdx & 7;            // n-tile, k-tile
    #pragma unroll
    for (int p = 0; p < 16; ++p) {                // stage, coalesced over n
        int kl = p * 4 + (tid >> 6), nl = tid & 63;
        int gk = tk * 64 + kl, gn = tn * 64 + nl;
        float v;
        if (isWo)            v = Wo[gk * 512 + gn];
        else if (gn < 512)   v = Wq[gk * 512 + gn];
        else                 v = Wkv[gk * 1024 + (gn - 512)];
        S[kl * 65 + nl] = v;
    }
    __syncthreads();
    u16* dst = isWo ? Wot : Wt;
    #pragma unroll
    for (int p = 0; p < 16; ++p) {                // write, coalesced over k
        int nl = p * 4 + (tid >> 6), kl = tid & 63;
        dst[(size_t)(tn * 64 + nl) * 512 + tk * 64 + kl] = f2bf(S[kl * 65 + nl]);
    }
}

// ---------------------------------------------------------------------------
// NT GEMM, double-buffered: C = A * B^T, K=512, bf16 MFMA 16x16x32, 4 waves,
// BK=32, XOR-swizzled LDS. MODE 0: bf16 store. MODE 1: fp32 store + bias.
// AF32=0: A staged via global_load_lds (bf16 source), as proven since R9.
// AF32=1: A source is fp32; reg-stage 2 chunks/thread (4x dwordx4), convert
//   via v_cvt_pk_bf16_f32, ds_write_b128 into the identical swizzled layout.
//   A regs pipelined 2 stages ahead (aReg parity buffers). vmcnt accounting:
//   steady-state 6 newest VMEM = {B(ks+1)x2, A(ks+2)x4} -> vmcnt(6);
//   ks=KSTEPS-2 -> vmcnt(2); last -> vmcnt(0). Frag reads/MFMA unchanged.
// R15: XCD-chunked bijective block swizzle.
// ---------------------------------------------------------------------------
template <int BM, int BN, int MODE, int AF32>
__global__ __launch_bounds__(256)
void gemm_nt(const void* __restrict__ Av, const u16* __restrict__ B,
             void* __restrict__ Cv, const float* __restrict__ bias,
             int lda, int ldb, int ldc) {
    constexpr int K = 512, BK = 32, KSTEPS = K / BK;
    constexpr int ACH = BM * 4;                  // A 16B-chunks per K-step
    constexpr int NCH = (BM + BN) * 4;
    constexpr int NLD = NCH / 256;               // chunks per thread per stage
    constexpr int ABYTES = BM * 64;
    constexpr int HALF = (BM + BN) * 64;         // one buffer
    constexpr int MI = BM / 32, NJ = BN / 32;
    __shared__ __align__(16) char lds[2 * HALF];
    const int tid  = threadIdx.x;
    const int lane = tid & 63, wave = tid >> 6;
    const int quad = lane >> 4, mrow = lane & 15;
    const int wm = wave >> 1, wn = wave & 1;

    // XCD-aware bijective swizzle: consecutive blocks round-robin XCDs, so
    // give XCD x the contiguous work chunk [x*nblk/8, (x+1)*nblk/8).
    const int nblk = gridDim.x * gridDim.y;
    int lid = blockIdx.y * gridDim.x + blockIdx.x;
    if (!(nblk & 7)) lid = (lid & 7) * (nblk >> 3) + (lid >> 3);
    const int bm = lid / (int)gridDim.x, bn = lid % (int)gridDim.x;

    const char* aLds[MI];
    const char* bLds[NJ];
    #pragma unroll
    for (int i = 0; i < MI; ++i) {
        int ra = wm * (BM / 2) + i * 16 + mrow;
        aLds[i] = lds + (ra * 4 + ((quad + (ra >> 1)) & 3)) * 16;
    }
    #pragma unroll
    for (int j = 0; j < NJ; ++j) {
        int rb = wn * (BN / 2) + j * 16 + mrow;
        bLds[j] = lds + ABYTES + (rb * 4 + ((quad + (rb >> 1)) & 3)) * 16;
    }

    f32x4 acc[MI][NJ] = {};

    if constexpr (!AF32) {
        // ---- original unified A+B global_load_lds staging ----
        const u16* A = (const u16*)Av;
        const char* gptr[NLD];
        char*       lptr[NLD];
        #pragma unroll
        for (int it = 0; it < NLD; ++it) {
            int c   = it * 256 + tid;                // chunk id, lane-consecutive
            int inB = (c >= ACH);
            int a   = inB ? c - ACH : c;
            int r   = a >> 2;                        // tile row
            int kc  = ((a & 3) - (r >> 1)) & 3;      // inverse swizzle
            int row = (inB ? bn * BN : bm * BM) + r;
            const u16* base = inB ? B : A;
            int ld = inB ? ldb : lda;
            gptr[it] = (const char*)(base + (size_t)row * ld + kc * 8);
            lptr[it] = (char*)lds + (it * 256 + wave * 64) * 16;   // wave-uniform
        }
        #pragma unroll
        for (int it = 0; it < NLD; ++it)             // prologue: stage 0 -> buf 0
            gload_lds16(gptr[it], lptr[it]);

        #pragma unroll
        for (int ks = 0; ks < KSTEPS; ++ks) {
            const int cur = ks & 1;
            if (ks + 1 < KSTEPS) {                   // prefetch next stage
                #pragma unroll
                for (int it = 0; it < NLD; ++it)
                    gload_lds16(gptr[it] + 2 * (ks + 1) * BK, lptr[it] + (cur ^ 1) * HALF);
                asm volatile("s_waitcnt vmcnt(%0)" :: "i"(NLD) : "memory");
            } else {
                asm volatile("s_waitcnt vmcnt(0)" ::: "memory");
            }
            asm volatile("s_barrier" ::: "memory");  // stage ks visible to all

            short8 af[MI], bf[NJ];
            #pragma unroll
            for (int i = 0; i < MI; ++i) af[i] = *(const short8*)(aLds[i] + cur * HALF);
            #pragma unroll
            for (int j = 0; j < NJ; ++j) bf[j] = *(const short8*)(bLds[j] + cur * HALF);
            #pragma unroll
            for (int i = 0; i < MI; ++i)
                #pragma unroll
                for (int j = 0; j < NJ; ++j)
                    acc[i][j] = __builtin_amdgcn_mfma_f32_16x16x32_bf16(af[i], bf[j], acc[i][j], 0, 0, 0);
            asm volatile("s_waitcnt lgkmcnt(0)" ::: "memory");
            asm volatile("s_barrier" ::: "memory");  // all waves done reading buf
        }
    } else {
        // ---- AF32: B via global_load_lds, A reg-staged from fp32 + cvt ----
        static_assert(BM == 128 && BN == 128, "AF32 path sized for 128x128");
        const float* xA = (const float*)Av;          // lda in floats (=512)
        const char* gB[2]; char* lB[2];
        #pragma unroll
        for (int it = 0; it < 2; ++it) {
            int a  = it * 256 + tid;                 // B chunk id
            int r  = a >> 2;
            int kc = ((a & 3) - (r >> 1)) & 3;       // inverse swizzle
            gB[it] = (const char*)(B + (size_t)(bn * BN + r) * ldb + kc * 8);
            lB[it] = (char*)lds + ABYTES + (it * 256 + wave * 64) * 16;
        }
        const float* pA[2];
        u32 aOff[2];
        #pragma unroll
        for (int c = 0; c < 2; ++c) {
            int a  = c * 256 + tid;                  // A chunk id (rows c*64..)
            int r  = a >> 2;
            int kc = ((a & 3) - (r >> 1)) & 3;
            pA[c]   = xA + (size_t)(bm * BM + r) * lda + kc * 8;
            aOff[c] = (u32)a * 16;
        }

        float4 aReg[2][2][2];                        // [stage parity][chunk][half]
        // prologue: B(0) -> buf0; A(0) regs; convert A(0) -> buf0; A(1) regs
        #pragma unroll
        for (int it = 0; it < 2; ++it)
            gload_lds16(gB[it], lB[it]);
        #pragma unroll
        for (int c = 0; c < 2; ++c)
            #pragma unroll
            for (int h = 0; h < 2; ++h)
                aReg[0][c][h] = *(const float4*)(pA[c] + h * 4);
        #pragma unroll
        for (int c = 0; c < 2; ++c)
            #pragma unroll
            for (int h = 0; h < 2; ++h)
                aReg[1][c][h] = *(const float4*)(pA[c] + 32 + h * 4);
        #pragma unroll
        for (int c = 0; c < 2; ++c) {                // convert stage 0 (compiler waits)
            float4 v0 = aReg[0][c][0], v1 = aReg[0][c][1];
            u32x4 w = { cvtpk(v0.x, v0.y), cvtpk(v0.z, v0.w),
                        cvtpk(v1.x, v1.y), cvtpk(v1.z, v1.w) };
            *(u32x4*)((char*)lds + aOff[c]) = w;
        }
        asm volatile("s_waitcnt lgkmcnt(0)" ::: "memory");

        #pragma unroll
        for (int ks = 0; ks < KSTEPS; ++ks) {
            const int cur = ks & 1;
            if (ks + 1 < KSTEPS) {
                #pragma unroll
                for (int it = 0; it < 2; ++it)       // B(ks+1) -> buf^1
                    gload_lds16(gB[it] + 2 * (ks + 1) * BK, lB[it] + (cur ^ 1) * HALF);
                if (ks + 2 < KSTEPS) {               // A(ks+2) regs (parity ks&1)
                    #pragma unroll
                    for (int c = 0; c < 2; ++c)
                        #pragma unroll
                        for (int h = 0; h < 2; ++h)
                            aReg[ks & 1][c][h] = *(const float4*)(pA[c] + (ks + 2) * 32 + h * 4);
                    // 6 newest VMEM = {B(ks+1)x2, A(ks+2)x4}; retire older
                    asm volatile("s_waitcnt vmcnt(6)" ::: "memory");
                } else {
                    // 2 newest = B(ks+1)x2; retire B(ks) and A(ks+1)
                    asm volatile("s_waitcnt vmcnt(2)" ::: "memory");
                }
                // convert A(ks+1) -> buf^1 (read next step)
                #pragma unroll
                for (int c = 0; c < 2; ++c) {
                    float4 v0 = aReg[(ks + 1) & 1][c][0], v1 = aReg[(ks + 1) & 1][c][1];
                    u32x4 w = { cvtpk(v0.x, v0.y), cvtpk(v0.z, v0.w),
                                cvtpk(v1.x, v1.y), cvtpk(v1.z, v1.w) };
                    *(u32x4*)((char*)lds + (cur ^ 1) * HALF + aOff[c]) = w;
                }
            } else {
                asm volatile("s_waitcnt vmcnt(0)" ::: "memory");
            }
            asm volatile("s_barrier" ::: "memory");  // stage ks visible to all

            short8 af[MI], bf[NJ];
            #pragma unroll
            for (int i = 0; i < MI; ++i) af[i] = *(const short8*)(aLds[i] + cur * HALF);
            #pragma unroll
            for (int j = 0; j < NJ; ++j) bf[j] = *(const short8*)(bLds[j] + cur * HALF);
            #pragma unroll
            for (int i = 0; i < MI; ++i)
                #pragma unroll
                for (int j = 0; j < NJ; ++j)
                    acc[i][j] = __builtin_amdgcn_mfma_f32_16x16x32_bf16(af[i], bf[j], acc[i][j], 0, 0, 0);
            asm volatile("s_waitcnt lgkmcnt(0)" ::: "memory");
            asm volatile("s_barrier" ::: "memory");  // all waves done reading buf
        }
    }

    // epilogue: D row = quad*4 + reg, col = lane&15 (m89-verified layout)
    #pragma unroll
    for (int i = 0; i < MI; ++i) {
        #pragma unroll
        for (int j = 0; j < NJ; ++j) {
            int colg = bn * BN + wn * (BN / 2) + j * 16 + mrow;
            #pragma unroll
            for (int r = 0; r < 4; ++r) {
                int rowg = bm * BM + wm * (BM / 2) + i * 16 + quad * 4 + r;
                if (MODE == 0) {
                    ((u16*)Cv)[(size_t)rowg * ldc + colg] = f2bf(acc[i][j][r]);
                } else {
                    ((float*)Cv)[(size_t)rowg * ldc + colg] = acc[i][j][r] + bias[colg];
                }
            }
        }
    }
}

// ---------------------------------------------------------------------------
// Attention v7+dot2 (R17, proven): one wave per (b, head-QUAD, ti).
// R15 XCD swizzle: each XCD owns 512 contiguous blocks -> window K/V reuse
// hits per-XCD L2. Phase 1: slot decode shared; 4 heads' QK dot via
// v_dot2_f32_bf16; batched softmax shfl chains. Phase 2: lane = (head, dim4);
// pj via per-wave LDS table; ONE dwordx2 load/slot covers all 4 heads;
// packed v_pk_fma_f32 accumulate; coalesced 8B store.
// ---------------------------------------------------------------------------
__global__ __launch_bounds__(256)
void attn_kernel(const u16* __restrict__ QKV, u16* __restrict__ O) {
    __shared__ float Pns[4][64];
    const int wave = threadIdx.x >> 6;
    // bijective XCD swizzle: 4096 blocks, XCD x owns contiguous 512-block run
    const int bsw = ((blockIdx.x & 7) << 9) | (blockIdx.x >> 3);
    const int wid  = bsw * 4 + wave;             // 0..16383
    const int lane = threadIdx.x & 63;
    const int b  = wid >> 13;             // 2
    const int hp = (wid >> 12) & 1;       // head quad (0..1)
    const int ti = wid & 4095;            // 4096
    const size_t baseQ = (size_t)b * T_TOK * NQKV;
    const size_t baseO = (size_t)b * T_TOK * DIM;
    const int hbase = hp * 256;           // u16-col of head quad start

    if (ti == 0) {                        // output row 0 = bos_v (4 heads)
        #pragma unroll
        for (int hd = 0; hd < 4; ++hd)
            O[baseO + hbase + hd * 64 + lane] =
                QKV[baseQ + 1024 + hbase + hd * 64 + lane];
        return;
    }
    const int t = ti - 1;                 // grid position, 0..4094
    const int f = t >> 10, hh = (t >> 5) & 31, ww = t & 31;

    // ---- per-lane slot decode (wave-uniform t; j varies per lane) — shared
    const int j = lane >> 2, g = lane & 3;
    int jm1 = j - 1;
    int dh9 = ((jm1 * 11) >> 5) - 1;      // j in 1..9: (j-1)/3 - 1
    int dw9 = jm1 - (dh9 + 1) * 3 - 1;    // j in 1..9: (j-1)%3 - 1
    int df = (j >= 1 && j <= 9) ? -1 : 0;
    int dh = (j >= 1 && j <= 9) ? dh9 : ((j >= 10 && j <= 12) ? -1 : 0);
    int dw = (j >= 1 && j <= 9) ? dw9 :
             ((j >= 10 && j <= 12) ? (j - 11) : ((j == 13) ? -1 : 0));
    int nf = f + df, nh = hh + dh, nw = ww + dw;
    int valid = (nf >= 0) && ((unsigned)nh < 32u) && ((unsigned)nw < 32u)
                && (j >= 1) && (j <= 14);
    int p = valid ? (t + 1 + df * 1024 + dh * 32 + dw) : 0;   // j==0 -> BOS
    int score_on = valid || (j == 0);

    // ---- phase 1: scores, four heads interleaved, packed bf16 dot2
    const u16* qbase = QKV + baseQ + (size_t)(t + 1) * NQKV + hbase + g * 16;
    const u16* kbase = QKV + baseQ + (size_t)p * NQKV + 512 + hbase + g * 16;
    u32x4 qa[4], qb[4], ka[4], kb[4];
    #pragma unroll
    for (int hd = 0; hd < 4; ++hd) {
        qa[hd] = *(const u32x4*)(qbase + hd * 64);
        qb[hd] = *(const u32x4*)(qbase + hd * 64 + 8);
        ka[hd] = *(const u32x4*)(kbase + hd * 64);
        kb[hd] = *(const u32x4*)(kbase + hd * 64 + 8);
    }
    float s[4] = {};
    #pragma unroll
    for (int i = 0; i < 4; ++i)
        #pragma unroll
        for (int hd = 0; hd < 4; ++hd) {
            s[hd] = dot2bf(qa[hd][i], ka[hd][i], s[hd]);
            s[hd] = dot2bf(qb[hd][i], kb[hd][i], s[hd]);
        }
    #pragma unroll
    for (int hd = 0; hd < 4; ++hd) {
        s[hd] += __shfl_xor(s[hd], 1);
        s[hd] += __shfl_xor(s[hd], 2);    // 4 g-lanes of slot j hold dot_j
        s[hd] *= 0.125f;                  // SCALE
        s[hd] = score_on ? s[hd] : -3.0e38f;
    }
    float m[4] = {s[0], s[1], s[2], s[3]};
    #pragma unroll
    for (int off = 4; off <= 32; off <<= 1)
        #pragma unroll
        for (int hd = 0; hd < 4; ++hd)
            m[hd] = fmaxf(m[hd], __shfl_xor(m[hd], off));
    float pe[4], l[4];
    #pragma unroll
    for (int hd = 0; hd < 4; ++hd) {
        pe[hd] = __expf(s[hd] - m[hd]);   // masked lanes -> 0
        l[hd] = pe[hd];
    }
    #pragma unroll
    for (int off = 4; off <= 32; off <<= 1)
        #pragma unroll
        for (int hd = 0; hd < 4; ++hd)
            l[hd] += __shfl_xor(l[hd], off);
    u32 voff = (u32)p * 3072u;            // byte offset of V row p (shared)

    // ---- pj table: Pns[wave][hd*16 + slot], written by g==0 lanes
    if ((lane & 3) == 0) {
        int slot = lane >> 2;
        #pragma unroll
        for (int hd = 0; hd < 4; ++hd)
            Pns[wave][hd * 16 + slot] = pe[hd] * __frcp_rn(l[hd]);
    }
    asm volatile("s_waitcnt lgkmcnt(0)" ::: "memory");

    // ---- phase 2: PV; lane = (head = lane>>4, dims (lane&15)*4 .. +3)
    const float* ptab = &Pns[wave][(lane >> 4) * 16];
    const char* vrow = (const char*)(QKV + baseQ + 1024 + hbase) + lane * 8;
    f32x2 a01 = {0.f, 0.f}, a23 = {0.f, 0.f};
    #pragma unroll
    for (int jj = 0; jj < 15; ++jj) {
        u32 o = (u32)__builtin_amdgcn_readlane((int)voff, jj * 4);
        float pj = ptab[jj];
        u64 v = *(const u64*)(vrow + o);          // 4 dims of lane's head
        u32 lo = (u32)v, hi = (u32)(v >> 32);
        f32x2 p2 = {pj, pj};
        f32x2 v0 = {__uint_as_float(lo << 16), __uint_as_float(lo & 0xffff0000u)};
        f32x2 v1 = {__uint_as_float(hi << 16), __uint_as_float(hi & 0xffff0000u)};
        a01 = __builtin_elementwise_fma(p2, v0, a01);
        a23 = __builtin_elementwise_fma(p2, v1, a23);
    }
    u64 pack = (u64)f2bf(a01.x) | ((u64)f2bf(a01.y) << 16) |
               ((u64)f2bf(a23.x) << 32) | ((u64)f2bf(a23.y) << 48);
    *(u64*)((char*)(O + baseO + (size_t)ti * DIM + hbase) + lane * 8) = pack;
}

// ---------------------------------------------------------------------------
// launch: cast(weights) -> gemm1 (x fp32 -> QKV, fused cast) -> attn -> gemm2
// ws layout (bytes): O 8M @0 | Wt 1.5M @8388608 | Wot 0.5M @9961472 |
//                    QKV 24M @10485760   (xb eliminated)
// ---------------------------------------------------------------------------
extern "C" void kernel_launch(void* const* d_in, const int* in_sizes, int n_in,
                              void* d_out, int out_size, void* d_ws, size_t ws_size,
                              hipStream_t stream) {
    const float* x   = (const float*)d_in[0];
    const float* Wq  = (const float*)d_in[1];
    const float* Wkv = (const float*)d_in[2];
    const float* Wo  = (const float*)d_in[3];
    const float* bo  = (const float*)d_in[4];
    float* out = (float*)d_out;
    char* ws = (char*)d_ws;

    u16* Wt  = (u16*)(ws + 8388608);
    u16* Wot = (u16*)(ws + 9961472);
    u16* QKV = (u16*)(ws + 10485760);
    u16* O   = (u16*)(ws + 0);

    cast_all_kernel<<<dim3(256), dim3(256), 0, stream>>>(Wq, Wkv, Wo, Wt, Wot);
    gemm_nt<128, 128, 0, 1><<<dim3(12, 64), dim3(256), 0, stream>>>(
        (const void*)x, Wt, (void*)QKV, nullptr, 512, 512, 1536);
    attn_kernel<<<dim3(4096), dim3(256), 0, stream>>>(QKV, O);
    gemm_nt<128, 64, 1, 0><<<dim3(8, 64), dim3(256), 0, stream>>>(
        (const void*)O, Wot, (void*)out, bo, 512, 512, 512);
}

// Round 5
// 127.698 us; speedup vs baseline: 1.0845x; 1.0002x over previous
//
#include <hip/hip_runtime.h>

// ---------------------------------------------------------------------------
// Sparse3DNA: x->QKV proj (bf16 MFMA GEMM), 3x3x3 causal window attention
// (+BOS), output proj. Shapes: b=2, T=4096 (4x32x32), DIM=512, 8 heads x 64.
// R19: both GEMMs switch 16x mfma_16x16x32 -> 8x mfma_32x32x16 per wave-K-step
// (same FLOPs/LDS traffic/acc regs, half the MFMA issue slots; frees issue BW
// for R18's fused A-convert VALU). Staging, swizzle, barriers, vmcnt identical.
// A/B frag: row=lane&31, k-chunk=lane>>5 (+2 for k>=16); C/D: col=lane&31,
// row=(reg&3)+8*(reg>>2)+4*(lane>>5) (m74/m101-verified).
// attn = R17 (v7+dot2). R15 XCD swizzles kept. Fills ~91us harness-fixed.
// ---------------------------------------------------------------------------

#define T_TOK   4096
#define DIM     512
#define NQKV    1536

typedef unsigned short u16;
typedef unsigned int   u32;
typedef unsigned long long u64;
typedef __attribute__((ext_vector_type(8))) short short8;   // 8 bf16 (4 VGPR)
typedef __attribute__((ext_vector_type(4))) float f32x4;
typedef __attribute__((ext_vector_type(16))) float f32x16;
typedef __attribute__((ext_vector_type(2))) float f32x2;
typedef __attribute__((ext_vector_type(4))) u32 u32x4;

__device__ __forceinline__ u16 f2bf(float f) {           // RNE float->bf16
    u32 u = __float_as_uint(f);
    return (u16)((u + 0x7fffu + ((u >> 16) & 1u)) >> 16);
}
__device__ __forceinline__ u32 cvtpk(float lo, float hi) {  // 2x f32 -> packed bf16 (RNE)
    u32 r;
    asm("v_cvt_pk_bf16_f32 %0, %1, %2" : "=v"(r) : "v"(lo), "v"(hi));
    return r;
}
__device__ __forceinline__ float dot2bf(u32 q, u32 k, float c) {
    // c += q.lo*k.lo + q.hi*k.hi  (packed bf16 pair dot, VOP3P)
    float r = c;
    asm("v_dot2_f32_bf16 %0, %1, %2, %0" : "+v"(r) : "v"(q), "v"(k));
    return r;
}

__device__ __forceinline__ void gload_lds16(const void* g, void* l) {
    // async global->LDS, 16B/lane; LDS dest = wave-uniform base + lane*16
    __builtin_amdgcn_global_load_lds(
        (const __attribute__((address_space(1))) void*)g,
        (__attribute__((address_space(3))) void*)l, 16, 0, 0);
}

// ---------------------------------------------------------------------------
// weight cast kernel (x-cast fused into gemm1 since R18).
//  blocks [0,192): Wt[n][k] = [Wq|Wk|Wv](k,n), LDS-tiled 64x64 transpose
//  blocks [192,256): Wot[n][k] = Wo[k][n], same
// ---------------------------------------------------------------------------
__global__ void cast_all_kernel(const float* __restrict__ Wq, const float* __restrict__ Wkv,
                                const float* __restrict__ Wo,
                                u16* __restrict__ Wt, u16* __restrict__ Wot) {
    __shared__ float S[64 * 65];
    int blk = blockIdx.x;
    int tid = threadIdx.x;
    int isWo = blk >= 192;
    int tIdx = isWo ? (blk - 192) : blk;
    int tn = tIdx >> 3, tk = tIdx & 7;            // n-tile, k-tile
    #pragma unroll
    for (int p = 0; p < 16; ++p) {                // stage, coalesced over n
        int kl = p * 4 + (tid >> 6), nl = tid & 63;
        int gk = tk * 64 + kl, gn = tn * 64 + nl;
        float v;
        if (isWo)            v = Wo[gk * 512 + gn];
        else if (gn < 512)   v = Wq[gk * 512 + gn];
        else                 v = Wkv[gk * 1024 + (gn - 512)];
        S[kl * 65 + nl] = v;
    }
    __syncthreads();
    u16* dst = isWo ? Wot : Wt;
    #pragma unroll
    for (int p = 0; p < 16; ++p) {                // write, coalesced over k
        int nl = p * 4 + (tid >> 6), kl = tid & 63;
        dst[(size_t)(tn * 64 + nl) * 512 + tk * 64 + kl] = f2bf(S[kl * 65 + nl]);
    }
}

// ---------------------------------------------------------------------------
// NT GEMM, double-buffered: C = A * B^T, K=512, 4 waves (2x2), BK=32,
// XOR-swizzled LDS, mfma_f32_32x32x16_bf16 (R19).
// MODE 0: bf16 store. MODE 1: fp32 store + bias.
// AF32=0: A staged via global_load_lds (bf16 source).
// AF32=1: A source fp32; reg-stage 4x dwordx4/thread, v_cvt_pk_bf16_f32,
//   ds_write_b128 into identical swizzled layout; A regs 2 stages ahead;
//   vmcnt(6) steady / 2 / 0 tail (6 newest = {B(ks+1)x2, A(ks+2)x4}).
// R15: XCD-chunked bijective block swizzle.
// ---------------------------------------------------------------------------
template <int BM, int BN, int MODE, int AF32>
__global__ __launch_bounds__(256)
void gemm_nt(const void* __restrict__ Av, const u16* __restrict__ B,
             void* __restrict__ Cv, const float* __restrict__ bias,
             int lda, int ldb, int ldc) {
    constexpr int K = 512, BK = 32, KSTEPS = K / BK;
    constexpr int ACH = BM * 4;                  // A 16B-chunks per K-step
    constexpr int NCH = (BM + BN) * 4;
    constexpr int NLD = NCH / 256;               // chunks per thread per stage
    constexpr int ABYTES = BM * 64;
    constexpr int HALF = (BM + BN) * 64;         // one buffer
    constexpr int MI2 = BM / 64, NJ2 = BN / 64;  // 32x32 tiles per wave
    __shared__ __align__(16) char lds[2 * HALF];
    const int tid  = threadIdx.x;
    const int lane = tid & 63, wave = tid >> 6;
    const int m32 = lane & 31, l5 = lane >> 5;
    const int wm = wave >> 1, wn = wave & 1;

    // XCD-aware bijective swizzle: consecutive blocks round-robin XCDs, so
    // give XCD x the contiguous work chunk [x*nblk/8, (x+1)*nblk/8).
    const int nblk = gridDim.x * gridDim.y;
    int lid = blockIdx.y * gridDim.x + blockIdx.x;
    if (!(nblk & 7)) lid = (lid & 7) * (nblk >> 3) + (lid >> 3);
    const int bm = lid / (int)gridDim.x, bn = lid % (int)gridDim.x;

    // 32x32 frag read pointers: row = base + m32; k-chunks (l5, l5+2)
    const char* aLds[MI2][2];
    const char* bLds[NJ2][2];
    #pragma unroll
    for (int i = 0; i < MI2; ++i) {
        int ra = wm * (BM / 2) + i * 32 + m32;
        #pragma unroll
        for (int c = 0; c < 2; ++c) {
            int ch = l5 + c * 2;
            aLds[i][c] = lds + (ra * 4 + ((ch + (ra >> 1)) & 3)) * 16;
        }
    }
    #pragma unroll
    for (int j = 0; j < NJ2; ++j) {
        int rb = wn * (BN / 2) + j * 32 + m32;
        #pragma unroll
        for (int c = 0; c < 2; ++c) {
            int ch = l5 + c * 2;
            bLds[j][c] = lds + ABYTES + (rb * 4 + ((ch + (rb >> 1)) & 3)) * 16;
        }
    }

    f32x16 acc[MI2][NJ2] = {};

    if constexpr (!AF32) {
        // ---- unified A+B global_load_lds staging ----
        const u16* A = (const u16*)Av;
        const char* gptr[NLD];
        char*       lptr[NLD];
        #pragma unroll
        for (int it = 0; it < NLD; ++it) {
            int c   = it * 256 + tid;                // chunk id, lane-consecutive
            int inB = (c >= ACH);
            int a   = inB ? c - ACH : c;
            int r   = a >> 2;                        // tile row
            int kc  = ((a & 3) - (r >> 1)) & 3;      // inverse swizzle
            int row = (inB ? bn * BN : bm * BM) + r;
            const u16* base = inB ? B : A;
            int ld = inB ? ldb : lda;
            gptr[it] = (const char*)(base + (size_t)row * ld + kc * 8);
            lptr[it] = (char*)lds + (it * 256 + wave * 64) * 16;   // wave-uniform
        }
        #pragma unroll
        for (int it = 0; it < NLD; ++it)             // prologue: stage 0 -> buf 0
            gload_lds16(gptr[it], lptr[it]);

        #pragma unroll
        for (int ks = 0; ks < KSTEPS; ++ks) {
            const int cur = ks & 1;
            if (ks + 1 < KSTEPS) {                   // prefetch next stage
                #pragma unroll
                for (int it = 0; it < NLD; ++it)
                    gload_lds16(gptr[it] + 2 * (ks + 1) * BK, lptr[it] + (cur ^ 1) * HALF);
                asm volatile("s_waitcnt vmcnt(%0)" :: "i"(NLD) : "memory");
            } else {
                asm volatile("s_waitcnt vmcnt(0)" ::: "memory");
            }
            asm volatile("s_barrier" ::: "memory");  // stage ks visible to all

            short8 af[MI2][2], bf[NJ2][2];
            #pragma unroll
            for (int i = 0; i < MI2; ++i)
                #pragma unroll
                for (int c = 0; c < 2; ++c)
                    af[i][c] = *(const short8*)(aLds[i][c] + cur * HALF);
            #pragma unroll
            for (int j = 0; j < NJ2; ++j)
                #pragma unroll
                for (int c = 0; c < 2; ++c)
                    bf[j][c] = *(const short8*)(bLds[j][c] + cur * HALF);
            #pragma unroll
            for (int i = 0; i < MI2; ++i)
                #pragma unroll
                for (int j = 0; j < NJ2; ++j) {
                    acc[i][j] = __builtin_amdgcn_mfma_f32_32x32x16_bf16(af[i][0], bf[j][0], acc[i][j], 0, 0, 0);
                    acc[i][j] = __builtin_amdgcn_mfma_f32_32x32x16_bf16(af[i][1], bf[j][1], acc[i][j], 0, 0, 0);
                }
            asm volatile("s_waitcnt lgkmcnt(0)" ::: "memory");
            asm volatile("s_barrier" ::: "memory");  // all waves done reading buf
        }
    } else {
        // ---- AF32: B via global_load_lds, A reg-staged from fp32 + cvt ----
        static_assert(BM == 128 && BN == 128, "AF32 path sized for 128x128");
        const float* xA = (const float*)Av;          // lda in floats (=512)
        const char* gB[2]; char* lB[2];
        #pragma unroll
        for (int it = 0; it < 2; ++it) {
            int a  = it * 256 + tid;                 // B chunk id
            int r  = a >> 2;
            int kc = ((a & 3) - (r >> 1)) & 3;       // inverse swizzle
            gB[it] = (const char*)(B + (size_t)(bn * BN + r) * ldb + kc * 8);
            lB[it] = (char*)lds + ABYTES + (it * 256 + wave * 64) * 16;
        }
        const float* pA[2];
        u32 aOff[2];
        #pragma unroll
        for (int c = 0; c < 2; ++c) {
            int a  = c * 256 + tid;                  // A chunk id (rows c*64..)
            int r  = a >> 2;
            int kc = ((a & 3) - (r >> 1)) & 3;
            pA[c]   = xA + (size_t)(bm * BM + r) * lda + kc * 8;
            aOff[c] = (u32)a * 16;
        }

        float4 aReg[2][2][2];                        // [stage parity][chunk][half]
        // prologue: B(0) -> buf0; A(0) regs; convert A(0) -> buf0; A(1) regs
        #pragma unroll
        for (int it = 0; it < 2; ++it)
            gload_lds16(gB[it], lB[it]);
        #pragma unroll
        for (int c = 0; c < 2; ++c)
            #pragma unroll
            for (int h = 0; h < 2; ++h)
                aReg[0][c][h] = *(const float4*)(pA[c] + h * 4);
        #pragma unroll
        for (int c = 0; c < 2; ++c)
            #pragma unroll
            for (int h = 0; h < 2; ++h)
                aReg[1][c][h] = *(const float4*)(pA[c] + 32 + h * 4);
        #pragma unroll
        for (int c = 0; c < 2; ++c) {                // convert stage 0 (compiler waits)
            float4 v0 = aReg[0][c][0], v1 = aReg[0][c][1];
            u32x4 w = { cvtpk(v0.x, v0.y), cvtpk(v0.z, v0.w),
                        cvtpk(v1.x, v1.y), cvtpk(v1.z, v1.w) };
            *(u32x4*)((char*)lds + aOff[c]) = w;
        }
        asm volatile("s_waitcnt lgkmcnt(0)" ::: "memory");

        #pragma unroll
        for (int ks = 0; ks < KSTEPS; ++ks) {
            const int cur = ks & 1;
            if (ks + 1 < KSTEPS) {
                #pragma unroll
                for (int it = 0; it < 2; ++it)       // B(ks+1) -> buf^1
                    gload_lds16(gB[it] + 2 * (ks + 1) * BK, lB[it] + (cur ^ 1) * HALF);
                if (ks + 2 < KSTEPS) {               // A(ks+2) regs (parity ks&1)
                    #pragma unroll
                    for (int c = 0; c < 2; ++c)
                        #pragma unroll
                        for (int h = 0; h < 2; ++h)
                            aReg[ks & 1][c][h] = *(const float4*)(pA[c] + (ks + 2) * 32 + h * 4);
                    // 6 newest VMEM = {B(ks+1)x2, A(ks+2)x4}; retire older
                    asm volatile("s_waitcnt vmcnt(6)" ::: "memory");
                } else {
                    // 2 newest = B(ks+1)x2; retire B(ks) and A(ks+1)
                    asm volatile("s_waitcnt vmcnt(2)" ::: "memory");
                }
                // convert A(ks+1) -> buf^1 (read next step)
                #pragma unroll
                for (int c = 0; c < 2; ++c) {
                    float4 v0 = aReg[(ks + 1) & 1][c][0], v1 = aReg[(ks + 1) & 1][c][1];
                    u32x4 w = { cvtpk(v0.x, v0.y), cvtpk(v0.z, v0.w),
                                cvtpk(v1.x, v1.y), cvtpk(v1.z, v1.w) };
                    *(u32x4*)((char*)lds + (cur ^ 1) * HALF + aOff[c]) = w;
                }
            } else {
                asm volatile("s_waitcnt vmcnt(0)" ::: "memory");
            }
            asm volatile("s_barrier" ::: "memory");  // stage ks visible to all

            short8 af[MI2][2], bf[NJ2][2];
            #pragma unroll
            for (int i = 0; i < MI2; ++i)
                #pragma unroll
                for (int c = 0; c < 2; ++c)
                    af[i][c] = *(const short8*)(aLds[i][c] + cur * HALF);
            #pragma unroll
            for (int j = 0; j < NJ2; ++j)
                #pragma unroll
                for (int c = 0; c < 2; ++c)
                    bf[j][c] = *(const short8*)(bLds[j][c] + cur * HALF);
            #pragma unroll
            for (int i = 0; i < MI2; ++i)
                #pragma unroll
                for (int j = 0; j < NJ2; ++j) {
                    acc[i][j] = __builtin_amdgcn_mfma_f32_32x32x16_bf16(af[i][0], bf[j][0], acc[i][j], 0, 0, 0);
                    acc[i][j] = __builtin_amdgcn_mfma_f32_32x32x16_bf16(af[i][1], bf[j][1], acc[i][j], 0, 0, 0);
                }
            asm volatile("s_waitcnt lgkmcnt(0)" ::: "memory");
            asm volatile("s_barrier" ::: "memory");  // all waves done reading buf
        }
    }

    // epilogue: 32x32 C/D layout — col = lane&31, row = (r&3)+8*(r>>2)+4*(lane>>5)
    #pragma unroll
    for (int i = 0; i < MI2; ++i) {
        #pragma unroll
        for (int j = 0; j < NJ2; ++j) {
            int colg = bn * BN + wn * (BN / 2) + j * 32 + m32;
            #pragma unroll
            for (int r = 0; r < 16; ++r) {
                int rowg = bm * BM + wm * (BM / 2) + i * 32 +
                           (r & 3) + 8 * (r >> 2) + 4 * l5;
                if (MODE == 0) {
                    ((u16*)Cv)[(size_t)rowg * ldc + colg] = f2bf(acc[i][j][r]);
                } else {
                    ((float*)Cv)[(size_t)rowg * ldc + colg] = acc[i][j][r] + bias[colg];
                }
            }
        }
    }
}

// ---------------------------------------------------------------------------
// Attention v7+dot2 (R17, proven): one wave per (b, head-QUAD, ti).
// R15 XCD swizzle: each XCD owns 512 contiguous blocks -> window K/V reuse
// hits per-XCD L2. Phase 1: slot decode shared; 4 heads' QK dot via
// v_dot2_f32_bf16; batched softmax shfl chains. Phase 2: lane = (head, dim4);
// pj via per-wave LDS table; ONE dwordx2 load/slot covers all 4 heads;
// packed v_pk_fma_f32 accumulate; coalesced 8B store.
// ---------------------------------------------------------------------------
__global__ __launch_bounds__(256)
void attn_kernel(const u16* __restrict__ QKV, u16* __restrict__ O) {
    __shared__ float Pns[4][64];
    const int wave = threadIdx.x >> 6;
    // bijective XCD swizzle: 4096 blocks, XCD x owns contiguous 512-block run
    const int bsw = ((blockIdx.x & 7) << 9) | (blockIdx.x >> 3);
    const int wid  = bsw * 4 + wave;             // 0..16383
    const int lane = threadIdx.x & 63;
    const int b  = wid >> 13;             // 2
    const int hp = (wid >> 12) & 1;       // head quad (0..1)
    const int ti = wid & 4095;            // 4096
    const size_t baseQ = (size_t)b * T_TOK * NQKV;
    const size_t baseO = (size_t)b * T_TOK * DIM;
    const int hbase = hp * 256;           // u16-col of head quad start

    if (ti == 0) {                        // output row 0 = bos_v (4 heads)
        #pragma unroll
        for (int hd = 0; hd < 4; ++hd)
            O[baseO + hbase + hd * 64 + lane] =
                QKV[baseQ + 1024 + hbase + hd * 64 + lane];
        return;
    }
    const int t = ti - 1;                 // grid position, 0..4094
    const int f = t >> 10, hh = (t >> 5) & 31, ww = t & 31;

    // ---- per-lane slot decode (wave-uniform t; j varies per lane) — shared
    const int j = lane >> 2, g = lane & 3;
    int jm1 = j - 1;
    int dh9 = ((jm1 * 11) >> 5) - 1;      // j in 1..9: (j-1)/3 - 1
    int dw9 = jm1 - (dh9 + 1) * 3 - 1;    // j in 1..9: (j-1)%3 - 1
    int df = (j >= 1 && j <= 9) ? -1 : 0;
    int dh = (j >= 1 && j <= 9) ? dh9 : ((j >= 10 && j <= 12) ? -1 : 0);
    int dw = (j >= 1 && j <= 9) ? dw9 :
             ((j >= 10 && j <= 12) ? (j - 11) : ((j == 13) ? -1 : 0));
    int nf = f + df, nh = hh + dh, nw = ww + dw;
    int valid = (nf >= 0) && ((unsigned)nh < 32u) && ((unsigned)nw < 32u)
                && (j >= 1) && (j <= 14);
    int p = valid ? (t + 1 + df * 1024 + dh * 32 + dw) : 0;   // j==0 -> BOS
    int score_on = valid || (j == 0);

    // ---- phase 1: scores, four heads interleaved, packed bf16 dot2
    const u16* qbase = QKV + baseQ + (size_t)(t + 1) * NQKV + hbase + g * 16;
    const u16* kbase = QKV + baseQ + (size_t)p * NQKV + 512 + hbase + g * 16;
    u32x4 qa[4], qb[4], ka[4], kb[4];
    #pragma unroll
    for (int hd = 0; hd < 4; ++hd) {
        qa[hd] = *(const u32x4*)(qbase + hd * 64);
        qb[hd] = *(const u32x4*)(qbase + hd * 64 + 8);
        ka[hd] = *(const u32x4*)(kbase + hd * 64);
        kb[hd] = *(const u32x4*)(kbase + hd * 64 + 8);
    }
    float s[4] = {};
    #pragma unroll
    for (int i = 0; i < 4; ++i)
        #pragma unroll
        for (int hd = 0; hd < 4; ++hd) {
            s[hd] = dot2bf(qa[hd][i], ka[hd][i], s[hd]);
            s[hd] = dot2bf(qb[hd][i], kb[hd][i], s[hd]);
        }
    #pragma unroll
    for (int hd = 0; hd < 4; ++hd) {
        s[hd] += __shfl_xor(s[hd], 1);
        s[hd] += __shfl_xor(s[hd], 2);    // 4 g-lanes of slot j hold dot_j
        s[hd] *= 0.125f;                  // SCALE
        s[hd] = score_on ? s[hd] : -3.0e38f;
    }
    float m[4] = {s[0], s[1], s[2], s[3]};
    #pragma unroll
    for (int off = 4; off <= 32; off <<= 1)
        #pragma unroll
        for (int hd = 0; hd < 4; ++hd)
            m[hd] = fmaxf(m[hd], __shfl_xor(m[hd], off));
    float pe[4], l[4];
    #pragma unroll
    for (int hd = 0; hd < 4; ++hd) {
        pe[hd] = __expf(s[hd] - m[hd]);   // masked lanes -> 0
        l[hd] = pe[hd];
    }
    #pragma unroll
    for (int off = 4; off <= 32; off <<= 1)
        #pragma unroll
        for (int hd = 0; hd < 4; ++hd)
            l[hd] += __shfl_xor(l[hd], off);
    u32 voff = (u32)p * 3072u;            // byte offset of V row p (shared)

    // ---- pj table: Pns[wave][hd*16 + slot], written by g==0 lanes
    if ((lane & 3) == 0) {
        int slot = lane >> 2;
        #pragma unroll
        for (int hd = 0; hd < 4; ++hd)
            Pns[wave][hd * 16 + slot] = pe[hd] * __frcp_rn(l[hd]);
    }
    asm volatile("s_waitcnt lgkmcnt(0)" ::: "memory");

    // ---- phase 2: PV; lane = (head = lane>>4, dims (lane&15)*4 .. +3)
    const float* ptab = &Pns[wave][(lane >> 4) * 16];
    const char* vrow = (const char*)(QKV + baseQ + 1024 + hbase) + lane * 8;
    f32x2 a01 = {0.f, 0.f}, a23 = {0.f, 0.f};
    #pragma unroll
    for (int jj = 0; jj < 15; ++jj) {
        u32 o = (u32)__builtin_amdgcn_readlane((int)voff, jj * 4);
        float pj = ptab[jj];
        u64 v = *(const u64*)(vrow + o);          // 4 dims of lane's head
        u32 lo = (u32)v, hi = (u32)(v >> 32);
        f32x2 p2 = {pj, pj};
        f32x2 v0 = {__uint_as_float(lo << 16), __uint_as_float(lo & 0xffff0000u)};
        f32x2 v1 = {__uint_as_float(hi << 16), __uint_as_float(hi & 0xffff0000u)};
        a01 = __builtin_elementwise_fma(p2, v0, a01);
        a23 = __builtin_elementwise_fma(p2, v1, a23);
    }
    u64 pack = (u64)f2bf(a01.x) | ((u64)f2bf(a01.y) << 16) |
               ((u64)f2bf(a23.x) << 32) | ((u64)f2bf(a23.y) << 48);
    *(u64*)((char*)(O + baseO + (size_t)ti * DIM + hbase) + lane * 8) = pack;
}

// ---------------------------------------------------------------------------
// launch: cast(weights) -> gemm1 (x fp32 -> QKV, fused cast) -> attn -> gemm2
// ws layout (bytes): O 8M @0 | Wt 1.5M @8388608 | Wot 0.5M @9961472 |
//                    QKV 24M @10485760
// ---------------------------------------------------------------------------
extern "C" void kernel_launch(void* const* d_in, const int* in_sizes, int n_in,
                              void* d_out, int out_size, void* d_ws, size_t ws_size,
                              hipStream_t stream) {
    const float* x   = (const float*)d_in[0];
    const float* Wq  = (const float*)d_in[1];
    const float* Wkv = (const float*)d_in[2];
    const float* Wo  = (const float*)d_in[3];
    const float* bo  = (const float*)d_in[4];
    float* out = (float*)d_out;
    char* ws = (char*)d_ws;

    u16* Wt  = (u16*)(ws + 8388608);
    u16* Wot = (u16*)(ws + 9961472);
    u16* QKV = (u16*)(ws + 10485760);
    u16* O   = (u16*)(ws + 0);

    cast_all_kernel<<<dim3(256), dim3(256), 0, stream>>>(Wq, Wkv, Wo, Wt, Wot);
    gemm_nt<128, 128, 0, 1><<<dim3(12, 64), dim3(256), 0, stream>>>(
        (const void*)x, Wt, (void*)QKV, nullptr, 512, 512, 1536);
    attn_kernel<<<dim3(4096), dim3(256), 0, stream>>>(QKV, O);
    gemm_nt<128, 64, 1, 0><<<dim3(8, 64), dim3(256), 0, stream>>>(
        (const void*)O, Wot, (void*)out, bo, 512, 512, 512);
}